// Round 1
// baseline (919.999 us; speedup 1.0000x reference)
//
#include <hip/hip_runtime.h>
#include <math.h>

#define B_ 64
#define I_ 4096
#define P_ 8      // Din
#define N_ 10
#define D_ 16
#define ND_ 160   // N*D
#define BND_ (B_*ND_)   // 10240
#define EPS_ 1e-7f

constexpr int WAVES_PB = 4;            // waves per block
constexpr int R_PW = 2;                // i per wave
constexpr int I_PB = WAVES_PB * R_PW;  // 8 i per block
constexpr int NBLK_ = I_ / I_PB;       // 512 blocks -> 2 blocks/CU on 256 CUs

__device__ __forceinline__ void load16(const float* __restrict__ p, float w[16]) {
    const float4* q = (const float4*)p;
    float4 a = q[0], b = q[1], c = q[2], d = q[3];
    w[0]=a.x; w[1]=a.y; w[2]=a.z; w[3]=a.w;
    w[4]=b.x; w[5]=b.y; w[6]=b.z; w[7]=b.w;
    w[8]=c.x; w[9]=c.y; w[10]=c.z; w[11]=c.w;
    w[12]=d.x; w[13]=d.y; w[14]=d.z; w[15]=d.w;
}

// One routing iteration: recompute u_hat on the fly, weight by c, accumulate
// partial s over this block's i-range. MODE 0: c = 1 (uniform; 0.1 scale applied
// in reduce). MODE 1: c = softmax_n(dot(u_hat, Vc)).
// Lane = b  -> W addresses wave-uniform (s_load), Vc in LDS [nd][b] (stride-1, no conflicts).
template<int MODE>
__global__ __launch_bounds__(256, 2)
void digitcaps_pass(const float* __restrict__ x, const float* __restrict__ W,
                    const float* __restrict__ Vc, float* __restrict__ part,
                    float* __restrict__ Sg, int use_part)
{
    __shared__ float smem[BND_];   // phase 1: Vc transposed [nd][b]; phase 2: block accumulator [nd][b]
    const int t = threadIdx.x;
    const int b = t & 63;
    const int w = __builtin_amdgcn_readfirstlane(t >> 6);

    if (MODE == 1) {
        for (int k = t; k < BND_; k += 256) {
            int bb = k / ND_;
            int nd = k - bb * ND_;
            smem[nd * B_ + bb] = Vc[k];
        }
        __syncthreads();
    }

    float acc[ND_];
#pragma unroll
    for (int j = 0; j < ND_; ++j) acc[j] = 0.f;

    const int ibase = blockIdx.x * I_PB + w * R_PW;

    for (int r = 0; r < R_PW; ++r) {
        const int i = ibase + r;                       // wave-uniform
        const float* __restrict__ Wi = W + (size_t)i * (N_ * P_ * D_);
        float xr[P_];
        {
            const float4* xp = (const float4*)(x + ((size_t)b * I_ + i) * P_);
            float4 a0 = xp[0], a1 = xp[1];
            xr[0]=a0.x; xr[1]=a0.y; xr[2]=a0.z; xr[3]=a0.w;
            xr[4]=a1.x; xr[5]=a1.y; xr[6]=a1.z; xr[7]=a1.w;
        }

        if (MODE == 0) {
#pragma unroll
            for (int n = 0; n < N_; ++n) {
#pragma unroll
                for (int p = 0; p < P_; ++p) {
                    float wv[16];
                    load16(Wi + (n * P_ + p) * D_, wv);
                    float xv = xr[p];
#pragma unroll
                    for (int d = 0; d < D_; ++d)
                        acc[n * D_ + d] = fmaf(xv, wv[d], acc[n * D_ + d]);
                }
            }
        } else {
            // sweep 1: logits[n] = dot_d(u_hat[n,:], Vc[b,n,:])
            float lg[N_];
#pragma unroll
            for (int n = 0; n < N_; ++n) {
                float tv[D_];
#pragma unroll
                for (int d = 0; d < D_; ++d) tv[d] = 0.f;
#pragma unroll
                for (int p = 0; p < P_; ++p) {
                    float wv[16];
                    load16(Wi + (n * P_ + p) * D_, wv);
                    float xv = xr[p];
#pragma unroll
                    for (int d = 0; d < D_; ++d) tv[d] = fmaf(xv, wv[d], tv[d]);
                }
                float l = 0.f;
#pragma unroll
                for (int d = 0; d < D_; ++d)
                    l = fmaf(tv[d], smem[(n * D_ + d) * B_ + b], l);
                lg[n] = l;
            }
            // softmax over n
            float m = lg[0];
#pragma unroll
            for (int n = 1; n < N_; ++n) m = fmaxf(m, lg[n]);
            float se = 0.f;
#pragma unroll
            for (int n = 0; n < N_; ++n) { lg[n] = __expf(lg[n] - m); se += lg[n]; }
            float inv = 1.f / se;
#pragma unroll
            for (int n = 0; n < N_; ++n) lg[n] *= inv;

            // sweep 2: recompute u_hat, accumulate c[n]*u_hat
#pragma unroll
            for (int n = 0; n < N_; ++n) {
                float tv[D_];
#pragma unroll
                for (int d = 0; d < D_; ++d) tv[d] = 0.f;
#pragma unroll
                for (int p = 0; p < P_; ++p) {
                    float wv[16];
                    load16(Wi + (n * P_ + p) * D_, wv);
                    float xv = xr[p];
#pragma unroll
                    for (int d = 0; d < D_; ++d) tv[d] = fmaf(xv, wv[d], tv[d]);
                }
                float cn = lg[n];
#pragma unroll
                for (int d = 0; d < D_; ++d)
                    acc[n * D_ + d] = fmaf(cn, tv[d], acc[n * D_ + d]);
            }
        }
    }

    // cross-wave reduce in LDS (repurpose smem), layout [nd][b] so lanes are stride-1
    __syncthreads();
    for (int k = t; k < BND_; k += 256) smem[k] = 0.f;
    __syncthreads();
#pragma unroll
    for (int j = 0; j < ND_; ++j) atomicAdd(&smem[j * B_ + b], acc[j]);
    __syncthreads();

    if (use_part) {
        float* po = part + (size_t)blockIdx.x * BND_;
        for (int k = t; k < BND_; k += 256) po[k] = smem[k];
    } else {
        for (int k = t; k < BND_; k += 256) atomicAdd(&Sg[k], smem[k]);
    }
}

// Sum block partials -> s, squash -> v, update cumulative Vc (or final out).
// Index k = nd*64 + b (partial layout); natural layout j = b*160 + nd.
__global__ void digitcaps_reduce(const float* __restrict__ part, const float* __restrict__ Sg,
                                 int use_part, float scale, int mode,
                                 float* __restrict__ Vc, float* __restrict__ out)
{
    int k = blockIdx.x * 256 + threadIdx.x;
    if (k >= BND_) return;
    float s = 0.f;
    if (use_part) {
#pragma unroll 8
        for (int p = 0; p < NBLK_; ++p) s += part[(size_t)p * BND_ + k];
    } else {
        s = Sg[k];
    }
    s *= scale;
    float sq = s * s;
    float v = s * (sq / ((1.f + sq) * sqrtf(sq + EPS_)));
    int b = k & (B_ - 1);
    int nd = k >> 6;
    int j = b * ND_ + nd;
    if (mode == 0)      Vc[j] = v;        // after iter 0: Vc = v0
    else if (mode == 1) Vc[j] += v;       // after iter 1: Vc = v0 + v1
    else                out[j] = v;       // after iter 2: final output [B,N,1,D]
}

extern "C" void kernel_launch(void* const* d_in, const int* in_sizes, int n_in,
                              void* d_out, int out_size, void* d_ws, size_t ws_size,
                              hipStream_t stream)
{
    const float* x = (const float*)d_in[0];   // [64, 4096, 8] f32
    const float* W = (const float*)d_in[1];   // [4096, 10, 8, 16] f32
    float* out = (float*)d_out;               // [64, 10, 1, 16] f32

    size_t part_f = (size_t)NBLK_ * BND_;
    size_t need = (part_f + 2 * BND_) * sizeof(float);
    float* part; float* Vc; float* Sg;
    int use_part = (ws_size >= need) ? 1 : 0;
    if (use_part) {
        part = (float*)d_ws;
        Vc   = part + part_f;
        Sg   = Vc + BND_;
    } else {
        part = nullptr;
        Sg   = (float*)d_ws;
        Vc   = Sg + BND_;
    }

    dim3 blk(256), grid(NBLK_), rgrid((BND_ + 255) / 256);

    for (int pass = 0; pass < 3; ++pass) {
        if (!use_part) hipMemsetAsync(Sg, 0, BND_ * sizeof(float), stream);
        if (pass == 0)
            digitcaps_pass<0><<<grid, blk, 0, stream>>>(x, W, nullptr, part, Sg, use_part);
        else
            digitcaps_pass<1><<<grid, blk, 0, stream>>>(x, W, Vc, part, Sg, use_part);
        digitcaps_reduce<<<rgrid, blk, 0, stream>>>(part, Sg, use_part,
                                                    pass == 0 ? 0.1f : 1.0f, pass, Vc, out);
    }
}

// Round 2
// 254.168 us; speedup vs baseline: 3.6196x; 3.6196x over previous
//
#include <hip/hip_runtime.h>
#include <math.h>

#define B_ 64
#define I_ 4096
#define P_ 8      // Din
#define N_ 10
#define D_ 16
#define ND_ 160   // N*D
#define BND_ (B_*ND_)   // 10240
#define EPS_ 1e-7f

constexpr int I_PB = 8;                // i per block
constexpr int NBLK_ = I_ / I_PB;       // 512 blocks -> 2 blocks/CU
constexpr int VC_STRIDE = 164;         // pad 160 -> 164 so b-groups land on disjoint bank halves

// Lane mapping: lane = g*16 + d, g = b-subgroup (0..3), d = output dim (0..15).
// Wave w covers b in {w*16 .. w*16+15} via 4 sub-iterations (bs).
// Each thread owns (b, d) and loops n=0..9: u_hat fragment tv[n] lives in regs,
// computed ONCE per (b,i), used for both logits (shfl-xor reduce over d) and acc.
// W for lane's d: wr[n*8+p] = W[i,n,p,d] -> 80 regs, shared across the 4 bs iters.
template<int MODE>
__global__ __launch_bounds__(256, 2)
void digitcaps_pass(const float* __restrict__ x, const float* __restrict__ W,
                    const float* __restrict__ Vc, float* __restrict__ part,
                    float* __restrict__ Sg, int use_part)
{
    __shared__ float vsh[(MODE == 1) ? (B_ * VC_STRIDE) : 64];
    const int t = threadIdx.x;
    const int lane = t & 63;
    const int w = t >> 6;        // wave 0..3
    const int d = lane & 15;
    const int g = lane >> 4;     // 0..3

    if (MODE == 1) {
        // stage Vc [b][n][d] -> LDS with padded b-stride (kills bank aliasing)
        for (int k = t; k < BND_; k += 256) {
            int bb = k / ND_;
            int nd = k - bb * ND_;
            vsh[bb * VC_STRIDE + nd] = Vc[k];
        }
        __syncthreads();
    }

    float acc[4][N_];
#pragma unroll
    for (int bs = 0; bs < 4; ++bs)
#pragma unroll
        for (int n = 0; n < N_; ++n) acc[bs][n] = 0.f;

    const int i0 = blockIdx.x * I_PB;

    for (int il = 0; il < I_PB; ++il) {
        const int i = i0 + il;
        const float* __restrict__ Wi = W + (size_t)i * (N_ * P_ * D_) + d;

        float wr[N_ * P_];
#pragma unroll
        for (int n = 0; n < N_; ++n)
#pragma unroll
            for (int p = 0; p < P_; ++p)
                wr[n * P_ + p] = Wi[(n * P_ + p) * D_];   // 64B-contiguous per 16 lanes

#pragma unroll
        for (int bs = 0; bs < 4; ++bs) {
            const int b = w * 16 + bs * 4 + g;
            float xv[P_];
            {
                const float4* xp = (const float4*)(x + ((size_t)b * I_ + i) * P_);
                float4 a0 = xp[0], a1 = xp[1];
                xv[0]=a0.x; xv[1]=a0.y; xv[2]=a0.z; xv[3]=a0.w;
                xv[4]=a1.x; xv[5]=a1.y; xv[6]=a1.z; xv[7]=a1.w;
            }

            float tv[N_];   // u_hat[b,i,n,d] for this lane's d
#pragma unroll
            for (int n = 0; n < N_; ++n) {
                float s = 0.f;
#pragma unroll
                for (int p = 0; p < P_; ++p)
                    s = fmaf(xv[p], wr[n * P_ + p], s);
                tv[n] = s;
            }

            if (MODE == 0) {
                // c uniform (softmax of zeros) -> 0.1 scale applied in reduce
#pragma unroll
                for (int n = 0; n < N_; ++n) acc[bs][n] += tv[n];
            } else {
                float lg[N_];
#pragma unroll
                for (int n = 0; n < N_; ++n) {
                    float pr = tv[n] * vsh[b * VC_STRIDE + n * D_ + d];
                    pr += __shfl_xor(pr, 1);
                    pr += __shfl_xor(pr, 2);
                    pr += __shfl_xor(pr, 4);
                    pr += __shfl_xor(pr, 8);
                    lg[n] = pr;          // full dot over d, broadcast to 16-lane group
                }
                float m = lg[0];
#pragma unroll
                for (int n = 1; n < N_; ++n) m = fmaxf(m, lg[n]);
                float se = 0.f;
#pragma unroll
                for (int n = 0; n < N_; ++n) { lg[n] = __expf(lg[n] - m); se += lg[n]; }
                float inv = 1.f / se;
#pragma unroll
                for (int n = 0; n < N_; ++n)
                    acc[bs][n] = fmaf(lg[n] * inv, tv[n], acc[bs][n]);
            }
        }
    }

    // Each thread owns distinct (b,n,d) -> straight stores, no intra-block reduce.
    if (use_part) {
        float* __restrict__ po = part + (size_t)blockIdx.x * BND_;
#pragma unroll
        for (int bs = 0; bs < 4; ++bs) {
            const int b = w * 16 + bs * 4 + g;
#pragma unroll
            for (int n = 0; n < N_; ++n)
                po[b * ND_ + n * D_ + d] = acc[bs][n];
        }
    } else {
#pragma unroll
        for (int bs = 0; bs < 4; ++bs) {
            const int b = w * 16 + bs * 4 + g;
#pragma unroll
            for (int n = 0; n < N_; ++n)
                atomicAdd(&Sg[b * ND_ + n * D_ + d], acc[bs][n]);
        }
    }
}

// Sum block partials -> s, squash -> v, update cumulative Vc (or final out).
// k = b*160 + n*16 + d, matches Vc and out [B,N,1,D] natural layout.
__global__ void digitcaps_reduce(const float* __restrict__ part, const float* __restrict__ Sg,
                                 int use_part, float scale, int mode,
                                 float* __restrict__ Vc, float* __restrict__ out)
{
    int k = blockIdx.x * 256 + threadIdx.x;
    if (k >= BND_) return;
    float s = 0.f;
    if (use_part) {
#pragma unroll 8
        for (int p = 0; p < NBLK_; ++p) s += part[(size_t)p * BND_ + k];
    } else {
        s = Sg[k];
    }
    s *= scale;
    float sq = s * s;
    float v = s * (sq / ((1.f + sq) * sqrtf(sq + EPS_)));
    if (mode == 0)      Vc[k] = v;        // after iter 0: Vc = v0
    else if (mode == 1) Vc[k] += v;       // after iter 1: Vc = v0 + v1
    else                out[k] = v;       // final output [B,N,1,D]
}

extern "C" void kernel_launch(void* const* d_in, const int* in_sizes, int n_in,
                              void* d_out, int out_size, void* d_ws, size_t ws_size,
                              hipStream_t stream)
{
    const float* x = (const float*)d_in[0];   // [64, 4096, 8] f32
    const float* W = (const float*)d_in[1];   // [4096, 10, 8, 16] f32
    float* out = (float*)d_out;               // [64, 10, 1, 16] f32

    size_t part_f = (size_t)NBLK_ * BND_;
    size_t need = (part_f + 2 * BND_) * sizeof(float);
    float* part; float* Vc; float* Sg;
    int use_part = (ws_size >= need) ? 1 : 0;
    if (use_part) {
        part = (float*)d_ws;
        Vc   = part + part_f;
        Sg   = Vc + BND_;
    } else {
        part = nullptr;
        Sg   = (float*)d_ws;
        Vc   = Sg + BND_;
    }

    dim3 blk(256), grid(NBLK_), rgrid((BND_ + 255) / 256);

    for (int pass = 0; pass < 3; ++pass) {
        if (!use_part) hipMemsetAsync(Sg, 0, BND_ * sizeof(float), stream);
        if (pass == 0)
            digitcaps_pass<0><<<grid, blk, 0, stream>>>(x, W, nullptr, part, Sg, use_part);
        else
            digitcaps_pass<1><<<grid, blk, 0, stream>>>(x, W, Vc, part, Sg, use_part);
        digitcaps_reduce<<<rgrid, blk, 0, stream>>>(part, Sg, use_part,
                                                    pass == 0 ? 0.1f : 1.0f, pass, Vc, out);
    }
}